// Round 4
// baseline (1260.059 us; speedup 1.0000x reference)
//
#include <hip/hip_runtime.h>
#include <stdint.h>

#define B 8192
#define T 512
#define K 24

// Exact first-index argmax over 24 values via tournament tree (depth 5).
// Every merge pairs a lower-index range against a higher one and keeps the
// lower on ties (strict > for the higher) => identical to jnp.argmax.
__device__ __forceinline__ void argmax24(const float s[K], float& mOut, int& pOut) {
    float v[12]; int idx[12];
#pragma unroll
    for (int p = 0; p < 12; ++p) {
        bool gt = s[2*p+1] > s[2*p];
        v[p]   = gt ? s[2*p+1] : s[2*p];
        idx[p] = gt ? 2*p+1 : 2*p;
    }
#pragma unroll
    for (int p = 0; p < 6; ++p) {
        bool gt = v[2*p+1] > v[2*p];
        v[p]   = gt ? v[2*p+1] : v[2*p];
        idx[p] = gt ? idx[2*p+1] : idx[2*p];
    }
#pragma unroll
    for (int p = 0; p < 3; ++p) {
        bool gt = v[2*p+1] > v[2*p];
        v[p]   = gt ? v[2*p+1] : v[2*p];
        idx[p] = gt ? idx[2*p+1] : idx[2*p];
    }
    bool g01 = v[1] > v[0];
    float vx = g01 ? v[1] : v[0];
    int   ix = g01 ? idx[1] : idx[0];
    bool g2  = v[2] > vx;
    mOut = g2 ? v[2] : vx;
    pOut = g2 ? idx[2] : ix;
}

// ---------------------------------------------------------------------------
// Forward Viterbi. ONE tag column per lane: 32-lane group per batch (lanes
// 24..31 masked off), 2 groups per wave, barrier-free (alpha exchange stays
// within one wave; program order + lgkmcnt give correctness, no barriers).
// Per-lane register demand ~90 (tc[24] pinned via asm so it cannot be
// rematerialized) -> fits the 128-VGPR / 4-waves-per-SIMD budget.
// WS=true: bp -> bp_ws[t][b][j] bytes (t-major for coalesced chase),
//          last_tag -> tag_ws[b][T-1].
// WS=false: bp -> out[b][t] bytes 72..95, last_tag -> out[b][0] word 18.
// ---------------------------------------------------------------------------
template<bool WS>
__global__ __launch_bounds__(256, 4) void crf_forward(
    const float* __restrict__ inp,    // [B, T, K]
    const float* __restrict__ trans,  // [K, K] (prev i -> cur j)
    float* __restrict__ out,
    uint8_t* __restrict__ bp_ws,      // [T, B, K] bytes
    uint8_t* __restrict__ tag_ws)     // [B, T] bytes
{
    __shared__ float alpha[2][4][2][K];   // [buf][wave][group][tag]

    const int tid  = threadIdx.x;
    const int w    = tid >> 6;
    const int lane = tid & 63;
    const int g    = lane >> 5;           // batch group within wave (0/1)
    const int lj   = lane & 31;           // tag column owned by this lane
    const int b    = blockIdx.x * 8 + w * 2 + g;

    if (lj >= K) return;                  // 16 idle lanes per wave

    // transition column lj in registers; asm-pin so it can't be remat'd/spilled
    float tc[K];
#pragma unroll
    for (int i = 0; i < K; ++i) tc[i] = trans[i * K + lj];
#pragma unroll
    for (int i = 0; i < K; ++i) asm volatile("" : "+v"(tc[i]));

    const float* eb  = inp + (size_t)b * T * K;
    uint32_t*    obw = (uint32_t*)out + (size_t)b * T * K;

    float* a0 = &alpha[0][w][g][0];
    float* a1 = &alpha[1][w][g][0];

    a0[lj] = eb[lj];                      // t = 0
    float e = eb[K + lj];                 // emission for t = 1 (prefetched)

    int cur = 0;
#pragma unroll 1
    for (int t = 1; t < T; ++t) {
        const float* ac = cur ? a1 : a0;
        float*       an = cur ? a0 : a1;

        // prefetch next step's emission (independent of this step's chain)
        float enext = eb[(size_t)(t + 1 < T ? t + 1 : t) * K + lj];

        float s[K];
#pragma unroll
        for (int c = 0; c < 6; ++c) {
            float4 v = *(const float4*)(ac + 4 * c);
            s[4*c]   = v.x + tc[4*c];
            s[4*c+1] = v.y + tc[4*c+1];
            s[4*c+2] = v.z + tc[4*c+2];
            s[4*c+3] = v.w + tc[4*c+3];
        }

        float m; int p;
        argmax24(s, m, p);

        an[lj] = m + e;

        if (WS) bp_ws[(size_t)t * (B * K) + (size_t)b * K + lj] = (uint8_t)p;
        else    ((uint8_t*)(obw + (size_t)t * K + 18))[lj] = (uint8_t)p;

        e = enext;
        cur ^= 1;
    }

    // last_tag = first-index argmax of alpha_{T-1}
    if (lj == 0) {
        const float* ac = cur ? a1 : a0;
        float a[K];
#pragma unroll
        for (int c = 0; c < 6; ++c) {
            float4 v = *(const float4*)(ac + 4 * c);
            a[4*c] = v.x; a[4*c+1] = v.y; a[4*c+2] = v.z; a[4*c+3] = v.w;
        }
        float m; int p;
        argmax24(a, m, p);
        if (WS) tag_ws[(size_t)b * T + (T - 1)] = (uint8_t)p;
        else    obw[18] = (uint32_t)p;
    }
}

// ---------------------------------------------------------------------------
// Chase (WS path): bp is [T][B][K] so every step's row loads are fully
// coalesced (24B/lane, contiguous across lanes) and chain-independent.
// 12-deep static-slot prefetch pipeline (~2.3 MB in flight chip-wide).
// Writes tags to tag_ws[b][t].
// ---------------------------------------------------------------------------
__global__ __launch_bounds__(64) void crf_chase_t(
    const uint8_t* __restrict__ bp,   // [T, B, K]
    uint8_t* __restrict__ tag)        // [B, T]
{
    const int b = blockIdx.x * 64 + threadIdx.x;
    uint8_t* tg = tag + (size_t)b * T;
    int cur = (int)tg[T - 1];

    const uint8_t* rowb = bp + (size_t)b * K;
    const size_t   rstr = (size_t)B * K;

    uint2 q[12][3];

#define CLOAD(SLOT, U) do {                                                   \
    int uc_ = (U) < 1 ? 1 : (U);                                              \
    const uint2* r_ = (const uint2*)(rowb + (size_t)uc_ * rstr);              \
    q[SLOT][0] = r_[0]; q[SLOT][1] = r_[1]; q[SLOT][2] = r_[2];               \
  } while (0)

#define CONSUME(SLOT, U) do {                                                 \
    int u_ = (U);                                                             \
    if (u_ >= 1) {                                                            \
      tg[u_] = (uint8_t)cur;                                                  \
      int idx_ = cur >> 2;                                                    \
      uint32_t wa_ = (idx_ & 1) ? q[SLOT][0].y : q[SLOT][0].x;                \
      uint32_t wb_ = (idx_ & 1) ? q[SLOT][1].y : q[SLOT][1].x;                \
      uint32_t wc_ = (idx_ & 1) ? q[SLOT][2].y : q[SLOT][2].x;                \
      uint32_t wab_ = (idx_ & 2) ? wb_ : wa_;                                 \
      uint32_t wd_  = (idx_ & 4) ? wc_ : wab_;                                \
      cur = (int)((wd_ >> ((cur & 3) * 8)) & 0xFF);                           \
    } else if (u_ == 0) {                                                     \
      tg[0] = (uint8_t)cur;                                                   \
    }                                                                         \
  } while (0)

#pragma unroll
    for (int s = 0; s < 12; ++s) CLOAD(s, 511 - s);

#pragma unroll 1
    for (int k = 0; k < 43; ++k) {        // 43*12 = 516 consumes, u = 511..-4
        int u0 = 511 - 12 * k;
#pragma unroll
        for (int s = 0; s < 12; ++s) {
            CONSUME(s, u0 - s);
            CLOAD(s, u0 - s - 12);
        }
    }
#undef CLOAD
#undef CONSUME
}

// ---------------------------------------------------------------------------
// Fallback chase (bp embedded in out) — unchanged from round 2 (correct).
// ---------------------------------------------------------------------------
__global__ __launch_bounds__(64) void crf_chase_f(float* __restrict__ out)
{
    const int b = blockIdx.x * 64 + threadIdx.x;
    uint32_t* obw = (uint32_t*)out + (size_t)b * T * K;

    uint32_t w[4][8][6];

#define LOADG(GG, SLOT) do {                                                  \
    int gg_ = (GG);                                                           \
    if (gg_ < 64) {                                                           \
      _Pragma("unroll")                                                       \
      for (int q_ = 0; q_ < 8; ++q_) {                                        \
        int u_ = 511 - 8 * gg_ - q_;                                          \
        const uint32_t* r_ = obw + (size_t)u_ * K + 18;                       \
        *(uint2*)&w[SLOT][q_][0] = *(const uint2*)(r_);                       \
        *(uint2*)&w[SLOT][q_][2] = *(const uint2*)(r_ + 2);                   \
        *(uint2*)&w[SLOT][q_][4] = *(const uint2*)(r_ + 4);                   \
      }                                                                       \
    }                                                                         \
  } while (0)

#define PROCG(GG, SLOT) do {                                                  \
    int gg_ = (GG);                                                           \
    _Pragma("unroll")                                                         \
    for (int q_ = 0; q_ < 8; ++q_) {                                          \
      int u_ = 511 - 8 * gg_ - q_;                                            \
      if (u_ > 0) {                                                           \
        int idx_ = cur >> 2;                                                  \
        uint32_t wA_ = (idx_ & 1) ? w[SLOT][q_][1] : w[SLOT][q_][0];          \
        uint32_t wB_ = (idx_ & 1) ? w[SLOT][q_][3] : w[SLOT][q_][2];          \
        uint32_t wC_ = (idx_ & 1) ? w[SLOT][q_][5] : w[SLOT][q_][4];          \
        uint32_t wAB_ = (idx_ & 2) ? wB_ : wA_;                               \
        uint32_t wd_  = (idx_ & 4) ? wC_ : wAB_;                              \
        int nxt_ = (int)((wd_ >> ((cur & 3) * 8)) & 0xFF);                    \
        obw[(size_t)u_ * K + 18] = (uint32_t)cur;                             \
        cur = nxt_;                                                           \
      } else {                                                                \
        obw[18] = (uint32_t)cur;                                              \
      }                                                                       \
    }                                                                         \
  } while (0)

    int cur = (int)obw[18];

    LOADG(0, 0); LOADG(1, 1); LOADG(2, 2); LOADG(3, 3);

#pragma unroll 1
    for (int base = 0; base < 60; base += 4) {
        PROCG(base + 0, 0); LOADG(base + 4, 0);
        PROCG(base + 1, 1); LOADG(base + 5, 1);
        PROCG(base + 2, 2); LOADG(base + 6, 2);
        PROCG(base + 3, 3); LOADG(base + 7, 3);
    }
    PROCG(60, 0); PROCG(61, 1); PROCG(62, 2); PROCG(63, 3);
#undef LOADG
#undef PROCG
}

// ---------------------------------------------------------------------------
// One-hot scatter: one thread per (b,t), fully coalesced 96B record writes.
// ---------------------------------------------------------------------------
template<bool WS>
__global__ __launch_bounds__(256) void crf_onehot(
    float* __restrict__ out, const uint8_t* __restrict__ tag_ws)
{
    const size_t idx = (size_t)blockIdx.x * 256 + threadIdx.x;  // < B*T
    uint32_t* rec = (uint32_t*)out + idx * K;
    int tag;
    if (WS) tag = (int)tag_ws[idx];
    else    tag = (int)rec[18];
#pragma unroll
    for (int c = 0; c < 6; ++c) {
        uint4 v;
        v.x = (tag == 4*c+0) ? 0x3F800000u : 0u;
        v.y = (tag == 4*c+1) ? 0x3F800000u : 0u;
        v.z = (tag == 4*c+2) ? 0x3F800000u : 0u;
        v.w = (tag == 4*c+3) ? 0x3F800000u : 0u;
        *(uint4*)(rec + 4*c) = v;
    }
}

extern "C" void kernel_launch(void* const* d_in, const int* in_sizes, int n_in,
                              void* d_out, int out_size, void* d_ws, size_t ws_size,
                              hipStream_t stream) {
    const float* inp   = (const float*)d_in[0];   // [8192, 512, 24]
    const float* trans = (const float*)d_in[1];   // [24, 24]
    float*       out   = (float*)d_out;           // [8192, 512, 24]

    const size_t need = (size_t)B * T * K + (size_t)B * T;  // bp + tags
    if (ws_size >= need) {
        uint8_t* bp = (uint8_t*)d_ws;                       // [T][B][K]
        uint8_t* tg = (uint8_t*)d_ws + (size_t)B * T * K;   // [B][T]
        crf_forward<true><<<B / 8, 256, 0, stream>>>(inp, trans, out, bp, tg);
        crf_chase_t<<<B / 64, 64, 0, stream>>>(bp, tg);
        crf_onehot<true><<<(B * T) / 256, 256, 0, stream>>>(out, tg);
    } else {
        crf_forward<false><<<B / 8, 256, 0, stream>>>(inp, trans, out, nullptr, nullptr);
        crf_chase_f<<<B / 64, 64, 0, stream>>>(out);
        crf_onehot<false><<<(B * T) / 256, 256, 0, stream>>>(out, nullptr);
    }
}

// Round 5
// 524.192 us; speedup vs baseline: 2.4038x; 2.4038x over previous
//
#include <hip/hip_runtime.h>
#include <stdint.h>

#define B 8192
#define T 512
#define K 24
#define BK (B * K)   // 196608

// ---------------------------------------------------------------------------
// Forward Viterbi. 64-thread block = ONE wave = 8 batches (8 lanes x 3 cols
// each). Alpha exchanged via LDS within the wave (in-order LDS pipe -> no
// barriers). Fused add+tournament keeps the live set tiny; waves_per_eu(1,1)
// gives the allocator a 512-reg budget so tc[3][24] stays resident.
// Tournament merges always pair lower-index range (left) vs higher (right),
// keeping left on ties (strict > for right) => identical to jnp.argmax.
// WS=true: bp -> bp_ws[t][b][j] (t-major), last_tag -> tag_ws[b][T-1].
// WS=false: bp -> out[b][t] bytes 72..95, last_tag -> out[b][0] word 18.
// ---------------------------------------------------------------------------
template<bool WS>
__global__ __launch_bounds__(64) __attribute__((amdgpu_waves_per_eu(1, 1)))
void crf_forward(const float* __restrict__ inp,    // [B, T, K]
                 const float* __restrict__ trans,  // [K, K] (prev i -> cur j)
                 float* __restrict__ out,
                 uint8_t* __restrict__ bp_ws,      // [T, B, K]
                 uint8_t* __restrict__ tag_ws)     // [B, T]
{
    __shared__ float alpha[2][8][K];

    const int lane = threadIdx.x;          // one wave per block
    const int g    = lane >> 3;            // batch group 0..7
    const int l    = lane & 7;             // lane within group
    const int c0   = 3 * l;                // this lane's columns c0..c0+2
    const int b    = blockIdx.x * 8 + g;   // 1024 blocks * 8 = 8192

    float tc[3][K];                        // 72 regs, budget 512 -> resident
#pragma unroll
    for (int j = 0; j < 3; ++j)
#pragma unroll
        for (int i = 0; i < K; ++i) tc[j][i] = trans[i * K + c0 + j];

    const float* ebl = inp + (size_t)b * T * K + c0;
    uint32_t*    obw = (uint32_t*)out + (size_t)b * T * K;

    uint8_t* bpp;
    size_t   bstride;
    if (WS) { bpp = bp_ws + (size_t)BK + (size_t)b * K + c0; bstride = BK; }
    else    { bpp = (uint8_t*)(obw + K + 18) + c0;           bstride = K * 4; }

    float* a0 = &alpha[0][g][0];
    float* a1 = &alpha[1][g][0];

    // t = 0
    a0[c0] = ebl[0]; a0[c0 + 1] = ebl[1]; a0[c0 + 2] = ebl[2];

    float e0 = ebl[K],     e1 = ebl[K + 1],     e2 = ebl[K + 2];      // e(1)
    float f0 = ebl[2 * K], f1 = ebl[2 * K + 1], f2 = ebl[2 * K + 2];  // e(2)

// One Viterbi step: read alpha (6 x b128 broadcast), fused add+tournament per
// column, write new alpha (3 x b32), store 3 bp bytes, advance bp pointer.
#define STEP(AC, AN, E0, E1, E2) do {                                         \
    float4 A_[6];                                                             \
    _Pragma("unroll")                                                         \
    for (int c = 0; c < 6; ++c) A_[c] = *(const float4*)((AC) + 4 * c);       \
    float m_[3]; int p_[3];                                                   \
    _Pragma("unroll")                                                         \
    for (int j = 0; j < 3; ++j) {                                             \
        float cw_[6]; int ci_[6];                                             \
        _Pragma("unroll")                                                     \
        for (int c = 0; c < 6; ++c) {                                         \
            float s0_ = A_[c].x + tc[j][4*c];                                 \
            float s1_ = A_[c].y + tc[j][4*c+1];                               \
            float s2_ = A_[c].z + tc[j][4*c+2];                               \
            float s3_ = A_[c].w + tc[j][4*c+3];                               \
            bool ga_ = s1_ > s0_; float wa_ = ga_ ? s1_ : s0_;                \
            int  ia_ = ga_ ? 4*c+1 : 4*c;                                     \
            bool gb_ = s3_ > s2_; float wb_ = gb_ ? s3_ : s2_;                \
            int  ib_ = gb_ ? 4*c+3 : 4*c+2;                                   \
            bool gc_ = wb_ > wa_;                                             \
            cw_[c] = gc_ ? wb_ : wa_; ci_[c] = gc_ ? ib_ : ia_;               \
        }                                                                     \
        bool h0_ = cw_[1] > cw_[0];                                           \
        float x0_ = h0_ ? cw_[1] : cw_[0]; int y0_ = h0_ ? ci_[1] : ci_[0];   \
        bool h1_ = cw_[3] > cw_[2];                                           \
        float x1_ = h1_ ? cw_[3] : cw_[2]; int y1_ = h1_ ? ci_[3] : ci_[2];   \
        bool h2_ = cw_[5] > cw_[4];                                           \
        float x2_ = h2_ ? cw_[5] : cw_[4]; int y2_ = h2_ ? ci_[5] : ci_[4];   \
        bool h3_ = x1_ > x0_;                                                 \
        float z_ = h3_ ? x1_ : x0_; int v_ = h3_ ? y1_ : y0_;                 \
        bool h4_ = x2_ > z_;                                                  \
        m_[j] = h4_ ? x2_ : z_; p_[j] = h4_ ? y2_ : v_;                       \
    }                                                                         \
    (AN)[c0] = m_[0] + (E0); (AN)[c0+1] = m_[1] + (E1);                       \
    (AN)[c0+2] = m_[2] + (E2);                                                \
    bpp[0] = (uint8_t)p_[0]; bpp[1] = (uint8_t)p_[1]; bpp[2] = (uint8_t)p_[2];\
    bpp += bstride;                                                           \
} while (0)

#pragma unroll 1
    for (int it = 0; it < 255; ++it) {
        const int t = 1 + 2 * it;               // 1,3,...,509
        // prefetch e(t+2) (t+2 <= 511, always valid)
        const float* pa = ebl + (size_t)(t + 2) * K;
        float g0 = pa[0], g1 = pa[1], g2 = pa[2];
        STEP(a0, a1, e0, e1, e2);               // step t
        // prefetch e(t+3), clamped (only last iter would run past the end)
        int tb = t + 3; tb = tb > 511 ? 511 : tb;
        const float* pb = ebl + (size_t)tb * K;
        float h0 = pb[0], h1 = pb[1], h2 = pb[2];
        STEP(a1, a0, f0, f1, f2);               // step t+1
        e0 = g0; e1 = g1; e2 = g2;
        f0 = h0; f1 = h1; f2 = h2;
    }
    STEP(a0, a1, e0, e1, e2);                   // t = 511 (final), a0 -> a1
#undef STEP

    // last_tag = first-index argmax of alpha_{T-1} (in a1); one lane per group
    if (l == 0) {
        float4 A[6];
#pragma unroll
        for (int c = 0; c < 6; ++c) A[c] = *(const float4*)(a1 + 4 * c);
        float cw[6]; int ci[6];
#pragma unroll
        for (int c = 0; c < 6; ++c) {
            bool ga = A[c].y > A[c].x;
            float wa = ga ? A[c].y : A[c].x; int ia = ga ? 4*c+1 : 4*c;
            bool gb = A[c].w > A[c].z;
            float wb = gb ? A[c].w : A[c].z; int ib = gb ? 4*c+3 : 4*c+2;
            bool gc = wb > wa;
            cw[c] = gc ? wb : wa; ci[c] = gc ? ib : ia;
        }
        bool h0 = cw[1] > cw[0];
        float x0 = h0 ? cw[1] : cw[0]; int y0 = h0 ? ci[1] : ci[0];
        bool h1 = cw[3] > cw[2];
        float x1 = h1 ? cw[3] : cw[2]; int y1 = h1 ? ci[3] : ci[2];
        bool h2 = cw[5] > cw[4];
        float x2 = h2 ? cw[5] : cw[4]; int y2 = h2 ? ci[5] : ci[4];
        bool h3 = x1 > x0;
        float z = h3 ? x1 : x0; int v = h3 ? y1 : y0;
        bool h4 = x2 > z;
        int p = h4 ? y2 : v;
        if (WS) tag_ws[(size_t)b * T + (T - 1)] = (uint8_t)p;
        else    obw[18] = (uint32_t)p;
    }
}

// ---------------------------------------------------------------------------
// Chase (WS path): bp is [T][B][K] -> per step a wave reads 64 consecutive
// batches' 24B rows (1536B contiguous, coalesced) and addresses are
// chain-independent. 16-deep prefetch pipeline (~3.1 MB in flight chip-wide).
// ---------------------------------------------------------------------------
__global__ __launch_bounds__(64) __attribute__((amdgpu_waves_per_eu(1, 1)))
void crf_chase_t(const uint8_t* __restrict__ bp,   // [T, B, K]
                 uint8_t* __restrict__ tag)        // [B, T]
{
    const int b = blockIdx.x * 64 + threadIdx.x;
    uint8_t* tg = tag + (size_t)b * T;
    int cur = (int)tg[T - 1];
    const uint8_t* rowb = bp + (size_t)b * K;

    uint2 q[16][3];   // 96 VGPRs, budget 512 -> resident

#define CLOAD(S, U) do { int u_ = (U); u_ = u_ < 1 ? 1 : u_;                  \
    const uint2* r_ = (const uint2*)(rowb + (size_t)u_ * BK);                 \
    q[S][0] = r_[0]; q[S][1] = r_[1]; q[S][2] = r_[2]; } while (0)

#define CONS(S, U) do { int u_ = (U);                                         \
    if (u_ >= 1) {                                                            \
        tg[u_] = (uint8_t)cur;                                                \
        int ix_ = cur >> 2;                                                   \
        uint32_t wa_ = (ix_ & 1) ? q[S][0].y : q[S][0].x;                     \
        uint32_t wb_ = (ix_ & 1) ? q[S][1].y : q[S][1].x;                     \
        uint32_t wc_ = (ix_ & 1) ? q[S][2].y : q[S][2].x;                     \
        uint32_t w1_ = (ix_ & 2) ? wb_ : wa_;                                 \
        uint32_t w2_ = (ix_ & 4) ? wc_ : w1_;                                 \
        cur = (int)((w2_ >> ((cur & 3) * 8)) & 0xFF);                         \
    } else if (u_ == 0) { tg[0] = (uint8_t)cur; } } while (0)

#pragma unroll
    for (int s = 0; s < 16; ++s) CLOAD(s, 511 - s);

#pragma unroll 1
    for (int k2 = 0; k2 < 32; ++k2) {
        const int u0 = 511 - 16 * k2;
#pragma unroll
        for (int s = 0; s < 16; ++s) {
            CONS(s, u0 - s);
            CLOAD(s, u0 - s - 16);
        }
    }
#undef CLOAD
#undef CONS
}

// ---------------------------------------------------------------------------
// Fallback chase (bp embedded in out) — round-2 proven version.
// ---------------------------------------------------------------------------
__global__ __launch_bounds__(64) __attribute__((amdgpu_waves_per_eu(1, 1)))
void crf_chase_f(float* __restrict__ out)
{
    const int b = blockIdx.x * 64 + threadIdx.x;
    uint32_t* obw = (uint32_t*)out + (size_t)b * T * K;

    uint32_t w[4][8][6];

#define LOADG(GG, SLOT) do {                                                  \
    int gg_ = (GG);                                                           \
    if (gg_ < 64) {                                                           \
      _Pragma("unroll")                                                       \
      for (int q_ = 0; q_ < 8; ++q_) {                                        \
        int u_ = 511 - 8 * gg_ - q_;                                          \
        const uint32_t* r_ = obw + (size_t)u_ * K + 18;                       \
        *(uint2*)&w[SLOT][q_][0] = *(const uint2*)(r_);                       \
        *(uint2*)&w[SLOT][q_][2] = *(const uint2*)(r_ + 2);                   \
        *(uint2*)&w[SLOT][q_][4] = *(const uint2*)(r_ + 4);                   \
      }                                                                       \
    }                                                                         \
  } while (0)

#define PROCG(GG, SLOT) do {                                                  \
    int gg_ = (GG);                                                           \
    _Pragma("unroll")                                                         \
    for (int q_ = 0; q_ < 8; ++q_) {                                          \
      int u_ = 511 - 8 * gg_ - q_;                                            \
      if (u_ > 0) {                                                           \
        int idx_ = cur >> 2;                                                  \
        uint32_t wA_ = (idx_ & 1) ? w[SLOT][q_][1] : w[SLOT][q_][0];          \
        uint32_t wB_ = (idx_ & 1) ? w[SLOT][q_][3] : w[SLOT][q_][2];          \
        uint32_t wC_ = (idx_ & 1) ? w[SLOT][q_][5] : w[SLOT][q_][4];          \
        uint32_t wAB_ = (idx_ & 2) ? wB_ : wA_;                               \
        uint32_t wd_  = (idx_ & 4) ? wC_ : wAB_;                              \
        int nxt_ = (int)((wd_ >> ((cur & 3) * 8)) & 0xFF);                    \
        obw[(size_t)u_ * K + 18] = (uint32_t)cur;                             \
        cur = nxt_;                                                           \
      } else {                                                                \
        obw[18] = (uint32_t)cur;                                              \
      }                                                                       \
    }                                                                         \
  } while (0)

    int cur = (int)obw[18];

    LOADG(0, 0); LOADG(1, 1); LOADG(2, 2); LOADG(3, 3);

#pragma unroll 1
    for (int base = 0; base < 60; base += 4) {
        PROCG(base + 0, 0); LOADG(base + 4, 0);
        PROCG(base + 1, 1); LOADG(base + 5, 1);
        PROCG(base + 2, 2); LOADG(base + 6, 2);
        PROCG(base + 3, 3); LOADG(base + 7, 3);
    }
    PROCG(60, 0); PROCG(61, 1); PROCG(62, 2); PROCG(63, 3);
#undef LOADG
#undef PROCG
}

// ---------------------------------------------------------------------------
// One-hot scatter: one thread per (b,t), 6 x b128 stores per record.
// ---------------------------------------------------------------------------
template<bool WS>
__global__ __launch_bounds__(256) void crf_onehot(
    float* __restrict__ out, const uint8_t* __restrict__ tag_ws)
{
    const size_t idx = (size_t)blockIdx.x * 256 + threadIdx.x;  // < B*T
    uint32_t* rec = (uint32_t*)out + idx * K;
    int tag;
    if (WS) tag = (int)tag_ws[idx];
    else    tag = (int)rec[18];
#pragma unroll
    for (int c = 0; c < 6; ++c) {
        uint4 v;
        v.x = (tag == 4*c+0) ? 0x3F800000u : 0u;
        v.y = (tag == 4*c+1) ? 0x3F800000u : 0u;
        v.z = (tag == 4*c+2) ? 0x3F800000u : 0u;
        v.w = (tag == 4*c+3) ? 0x3F800000u : 0u;
        *(uint4*)(rec + 4*c) = v;
    }
}

extern "C" void kernel_launch(void* const* d_in, const int* in_sizes, int n_in,
                              void* d_out, int out_size, void* d_ws, size_t ws_size,
                              hipStream_t stream) {
    const float* inp   = (const float*)d_in[0];   // [8192, 512, 24]
    const float* trans = (const float*)d_in[1];   // [24, 24]
    float*       out   = (float*)d_out;           // [8192, 512, 24]

    const size_t need = (size_t)B * T * K + (size_t)B * T;  // bp + tags
    if (ws_size >= need) {
        uint8_t* bp = (uint8_t*)d_ws;                       // [T][B][K]
        uint8_t* tg = (uint8_t*)d_ws + (size_t)B * T * K;   // [B][T]
        crf_forward<true><<<B / 8, 64, 0, stream>>>(inp, trans, out, bp, tg);
        crf_chase_t<<<B / 64, 64, 0, stream>>>(bp, tg);
        crf_onehot<true><<<(B * T) / 256, 256, 0, stream>>>(out, tg);
    } else {
        crf_forward<false><<<B / 8, 64, 0, stream>>>(inp, trans, out, nullptr, nullptr);
        crf_chase_f<<<B / 64, 64, 0, stream>>>(out);
        crf_onehot<false><<<(B * T) / 256, 256, 0, stream>>>(out, nullptr);
    }
}